// Round 6
// baseline (107.883 us; speedup 1.0000x reference)
//
#include <hip/hip_runtime.h>

#define NROWS 8192
#define DIMX  128          // raw feature dims
#define DIM2  160          // padded K: 128 data + 1 sq-dim + 10 one-hot + 21 zero
#define NCLS  10
#define GAPV  0.4f
#define BIAS  2048.0f      // 2 * 32 * 32
#define C0    128.0f       // sq centering constant
#define RGR   128          // rows per block (4 waves x 32 rows)
#define NRG   (NROWS / RGR)      // 64 rowgroups
#define CHUNK 512          // cols per block
#define NCHUNK (NROWS / CHUNK)   // 16 col-chunks
#define SLAB  32           // cols staged per LDS buffer
#define NSLAB (CHUNK / SLAB)     // 16 slabs
#define LDST  168          // LDS row stride in shorts (336B: 16B-aligned, <=2-way bank = free)

typedef __attribute__((ext_vector_type(8))) short bf16x8;
typedef __attribute__((ext_vector_type(4))) float f32x4;

// monotone float <-> uint encoding so atomicMax/atomicMin on uint order like floats
__device__ __forceinline__ unsigned fenc(float f) {
  unsigned u = __float_as_uint(f);
  return (u & 0x80000000u) ? ~u : (u | 0x80000000u);
}
__device__ __forceinline__ float fdec(unsigned u) {
  return (u & 0x80000000u) ? __uint_as_float(u & 0x7fffffffu) : __uint_as_float(~u);
}
__device__ __forceinline__ short f2bf(float f) {  // RNE fp32->bf16
  unsigned u = __float_as_uint(f);
  u += 0x7fffu + ((u >> 16) & 1u);
  return (short)(u >> 16);
}

// ---- kernel 1: build augmented bf16 arrays, sq, init accumulators, confusion, zero counters ----
// xa[row]  = [bf16(x), 1.0,         +32*onehot(cls), 0...]   (A operand)
// xbm[row] = [bf16(x), -(sq-128)/2, -32*onehot(cls), 0...]   (B operand)
// => g = dot(xa_i, xbm_j) = dot_ij - (sq_j-128)/2 - 1024*[same]
//    h = 128 - 2g = sq_j - 2dot + 2048*[same]
__global__ __launch_bounds__(256) void prep_k(const float* __restrict__ x,
                                              const int* __restrict__ tgt,
                                              const float* __restrict__ pred,
                                              short* __restrict__ xa,
                                              short* __restrict__ xbm,
                                              float* __restrict__ sq,
                                              unsigned* __restrict__ emax,
                                              unsigned* __restrict__ emin,
                                              int* __restrict__ conf,
                                              unsigned* __restrict__ ctrs) {
  if (blockIdx.x == 0 && threadIdx.x < NRG + 3) ctrs[threadIdx.x] = 0u;  // rg_done[64], g_done, Ssum, Csum

  const int wave = threadIdx.x >> 6;
  const int lane = threadIdx.x & 63;
  const int row  = blockIdx.x * 4 + wave;
  const float* p = x + (size_t)row * DIMX;
  const float a = p[lane];
  const float b = p[lane + 64];
  float s = a * a + b * b;
  #pragma unroll
  for (int m = 1; m < 64; m <<= 1) s += __shfl_xor(s, m, 64);

  short* pa = xa  + (size_t)row * DIM2;
  short* pb = xbm + (size_t)row * DIM2;
  pa[lane] = f2bf(a); pa[lane + 64] = f2bf(b);
  pb[lane] = f2bf(a); pb[lane + 64] = f2bf(b);

  const int cls = tgt[row];
  if (lane < 32) {
    short va, vb;
    if (lane == 0)          { va = (short)0x3F80; vb = f2bf(-0.5f * (s - C0)); }
    else if (lane <= NCLS)  { const bool hit = (lane - 1) == cls;
                              va = hit ? (short)0x4200 : (short)0;
                              vb = hit ? (short)0xC200 : (short)0; }
    else                    { va = 0; vb = 0; }
    pa[128 + lane] = va;
    pb[128 + lane] = vb;
  }

  if (lane == 0) {
    sq[row]   = s;
    emax[row] = fenc(-INFINITY);
    emin[row] = fenc(INFINITY);
    const float* pp = pred + (size_t)row * NCLS;
    float v[NCLS];
    #pragma unroll
    for (int c = 0; c < NCLS; ++c) v[c] = pp[c];
    float m1 = v[0]; int i1 = 0;
    #pragma unroll
    for (int c = 1; c < NCLS; ++c)
      if (v[c] > m1) { m1 = v[c]; i1 = c; }
    float m2 = -INFINITY, sum = 0.f;
    #pragma unroll
    for (int c = 0; c < NCLS; ++c) {
      sum += __expf(v[c] - m1);
      if (c != i1) m2 = fmaxf(m2, v[c]);
    }
    const float d01 = (1.f - __expf(m2 - m1)) / sum;
    conf[row] = (d01 <= GAPV) || (i1 != cls);
  }
}

// ---- kernel 2: Gram + hard mining + fused finalize ----
// TLP-focused retile: 4 waves/block, each owns only 32 rows (A = 2x5 frags, 40 VGPRs),
// __launch_bounds__(256,4) -> 4 waves/SIMD, 16 waves/CU, 4 blocks/CU (LDS 21.5 KB).
// B: 512-col chunk through double-buffered 32-col LDS slabs.
__global__ __launch_bounds__(256, 4) void gram_k(const short* __restrict__ xa,
                                                 const short* __restrict__ xbm,
                                                 const float* __restrict__ sq,
                                                 const int* __restrict__ conf,
                                                 unsigned* __restrict__ emax,
                                                 unsigned* __restrict__ emin,
                                                 unsigned* __restrict__ ctrs,
                                                 float* __restrict__ out) {
  __shared__ short lds[2][SLAB * LDST];
  __shared__ float red[2][4];
  __shared__ int   flag;
  const int tid  = threadIdx.x;
  const int wave = tid >> 6;
  const int lane = tid & 63;
  const int quad = lane >> 4;   // 0..3
  const int m16  = lane & 15;   // 0..15
  const int i0    = blockIdx.x * RGR + wave * 32;
  const int jbase = blockIdx.y * CHUNK;

  unsigned* rg_done = ctrs;                 // [NRG]
  unsigned* g_done  = ctrs + NRG;
  float*    Ssum    = (float*)(ctrs + NRG + 1);
  float*    Csum    = (float*)(ctrs + NRG + 2);

  // A fragments: rows i0 + r*16 + m16, k = ks*32 + quad*8 + e  (40 VGPRs)
  bf16x8 A[2][5];
  #pragma unroll
  for (int r = 0; r < 2; ++r) {
    const short* pa = xa + (size_t)(i0 + r * 16 + m16) * DIM2 + quad * 8;
    #pragma unroll
    for (int ks = 0; ks < 5; ++ks)
      A[r][ks] = *(const bf16x8*)(pa + ks * 32);
  }
  #pragma unroll
  for (int r = 0; r < 2; ++r)
    #pragma unroll
    for (int ks = 0; ks < 5; ++ks)
      asm volatile("" : "+v"(A[r][ks]));   // pin: no remat of A loads in hot loop

  float gmin[2][4], gmax[2][4];
  #pragma unroll
  for (int r = 0; r < 2; ++r)
    #pragma unroll
    for (int q = 0; q < 4; ++q) { gmin[r][q] = INFINITY; gmax[r][q] = -INFINITY; }

  // staging: thread covers col scol (0..31), seg (0..7) -> 5 x 8B pieces
  const int scol = tid >> 3;
  const int seg  = tid & 7;
  const short* gsrc = xbm + (size_t)(jbase + scol) * DIM2 + seg * 4;

  {  // prologue: slab 0 -> lds[0]
    uint2 st[5];
    #pragma unroll
    for (int u = 0; u < 5; ++u) st[u] = *(const uint2*)(gsrc + u * 32);
    short* dst = (short*)lds + scol * LDST + seg * 4;
    #pragma unroll
    for (int u = 0; u < 5; ++u) *(uint2*)(dst + u * 32) = st[u];
  }
  __syncthreads();

  for (int s = 0; s < NSLAB; ++s) {
    // issue prefetch for slab s+1 (wrapped on last iter -> harmless rewrite of slab0 data)
    const int snext = (s + 1) & (NSLAB - 1);
    const short* gn = gsrc + (size_t)snext * SLAB * DIM2;
    uint2 nx[5];
    #pragma unroll
    for (int u = 0; u < 5; ++u) nx[u] = *(const uint2*)(gn + u * 32);

    // compute from lds[s&1] while prefetch flies (2 x 16-col tiles, 20 MFMAs/jt)
    const short* buf = lds[s & 1];
    #pragma unroll
    for (int jt = 0; jt < SLAB / 16; ++jt) {
      const short* pb = buf + (jt * 16 + m16) * LDST + quad * 8;
      bf16x8 B[5];
      #pragma unroll
      for (int ks = 0; ks < 5; ++ks) B[ks] = *(const bf16x8*)(pb + ks * 32);

      f32x4 acc[2];
      #pragma unroll
      for (int r = 0; r < 2; ++r) acc[r] = (f32x4){0.f, 0.f, 0.f, 0.f};
      #pragma unroll
      for (int ks = 0; ks < 5; ++ks)
        #pragma unroll
        for (int r = 0; r < 2; ++r)
          acc[r] = __builtin_amdgcn_mfma_f32_16x16x32_bf16(A[r][ks], B[ks], acc[r], 0, 0, 0);

      #pragma unroll
      for (int r = 0; r < 2; ++r)
        #pragma unroll
        for (int q = 0; q < 4; ++q) {
          gmin[r][q] = fminf(gmin[r][q], acc[r][q]);
          gmax[r][q] = fmaxf(gmax[r][q], acc[r][q]);
        }
    }

    // store prefetched slab into the other buffer (vmcnt wait lands here, post-MFMA)
    short* dst = (short*)lds + ((s + 1) & 1) * (SLAB * LDST) + scol * LDST + seg * 4;
    #pragma unroll
    for (int u = 0; u < 5; ++u) *(uint2*)(dst + u * 32) = nx[u];
    __syncthreads();
  }

  // reduce over the 16 cols held across m16 lanes (quad bits preserved)
  #pragma unroll
  for (int m = 1; m <= 8; m <<= 1)
    #pragma unroll
    for (int r = 0; r < 2; ++r)
      #pragma unroll
      for (int q = 0; q < 4; ++q) {
        gmin[r][q] = fminf(gmin[r][q], __shfl_xor(gmin[r][q], m, 64));
        gmax[r][q] = fmaxf(gmax[r][q], __shfl_xor(gmax[r][q], m, 64));
      }

  if (m16 == 0) {
    #pragma unroll
    for (int r = 0; r < 2; ++r)
      #pragma unroll
      for (int q = 0; q < 4; ++q) {
        const int row = i0 + r * 16 + quad * 4 + q;
        // hardest positive: max_same(sq_j - 2dot) = (128 - 2*gmin) - 2048
        atomicMax(&emax[row], fenc(C0 - 2.f * gmin[r][q] - BIAS));
        // hardest negative: min_diff(sq_j - 2dot) = 128 - 2*gmax
        atomicMin(&emin[row], fenc(C0 - 2.f * gmax[r][q]));
      }
  }

  // ---- fused finalize: last chunk-block of this rowgroup handles its 128 rows ----
  __syncthreads();   // all atomics drained before counter bump
  if (tid == 0) {
    __threadfence();
    flag = (atomicAdd(&rg_done[blockIdx.x], 1u) == NCHUNK - 1u);
  }
  __syncthreads();
  if (!flag) return;

  float ps = 0.f, pc = 0.f;
  if (tid < RGR) {
    const int row = blockIdx.x * RGR + tid;
    if (conf[row]) {
      const float hi = fdec(atomicMax(&emax[row], 0u));           // identity read
      const float lo = fdec(atomicMin(&emin[row], 0xFFFFFFFFu));  // identity read
      const float ap = sqrtf(fmaxf(sq[row] + hi, 1e-12f));
      const float an = sqrtf(fmaxf(sq[row] + lo, 1e-12f));
      ps = fmaxf(ap - an, 0.f);
      pc = 1.f;
    }
  }
  #pragma unroll
  for (int m = 1; m < 64; m <<= 1) {
    ps += __shfl_xor(ps, m, 64);
    pc += __shfl_xor(pc, m, 64);
  }
  if (lane == 0) { red[0][wave] = ps; red[1][wave] = pc; }
  __syncthreads();
  if (tid == 0) {
    float S = red[0][0] + red[0][1] + red[0][2] + red[0][3];
    float C = red[1][0] + red[1][1] + red[1][2] + red[1][3];
    atomicAdd(Ssum, S);
    atomicAdd(Csum, C);
    __threadfence();
    if (atomicAdd(g_done, 1u) == NRG - 1u) {
      const float St = atomicAdd(Ssum, 0.f);
      const float Ct = atomicAdd(Csum, 0.f);
      out[0] = (Ct > 0.f) ? (St / fmaxf(Ct, 1.f)) : 0.f;
    }
  }
}

extern "C" void kernel_launch(void* const* d_in, const int* in_sizes, int n_in,
                              void* d_out, int out_size, void* d_ws, size_t ws_size,
                              hipStream_t stream) {
  const float* x    = (const float*)d_in[0];
  const float* pred = (const float*)d_in[1];
  const int*   tgt  = (const int*)d_in[2];
  float* out = (float*)d_out;

  char* w = (char*)d_ws;
  const size_t arr_bytes = (size_t)NROWS * DIM2 * 2;  // 2.56 MiB each
  short*    xa   = (short*)w;
  short*    xbm  = (short*)(w + arr_bytes);
  float*    sq   = (float*)(w + 2 * arr_bytes);
  unsigned* emax = (unsigned*)(w + 2 * arr_bytes + (size_t)NROWS * 4);
  unsigned* emin = (unsigned*)(w + 2 * arr_bytes + (size_t)NROWS * 8);
  int*      conf = (int*)(w + 2 * arr_bytes + (size_t)NROWS * 12);
  unsigned* ctrs = (unsigned*)(w + 2 * arr_bytes + (size_t)NROWS * 16);  // rg_done[64], g_done, Ssum, Csum

  hipLaunchKernelGGL(prep_k, dim3(NROWS / 4), dim3(256), 0, stream,
                     x, tgt, pred, xa, xbm, sq, emax, emin, conf, ctrs);
  hipLaunchKernelGGL(gram_k, dim3(NRG, NCHUNK), dim3(256), 0, stream,
                     xa, xbm, sq, conf, emax, emin, ctrs, out);
}

// Round 7
// 107.085 us; speedup vs baseline: 1.0075x; 1.0075x over previous
//
#include <hip/hip_runtime.h>

#define NROWS 8192
#define DIMX  128          // raw feature dims
#define DIM2  160          // padded K: 128 data + 1 sq-dim + 10 one-hot + 21 zero
#define NCLS  10
#define GAPV  0.4f
#define BIAS  2048.0f      // 2 * 32 * 32
#define C0    128.0f       // sq centering constant
#define RGR   256          // rows per block (4 waves x 64 rows)
#define NRG   (NROWS / RGR)      // 32 rowgroups
#define CHUNK 512          // cols per block
#define NCHUNK (NROWS / CHUNK)   // 16 col-chunks
#define NJ    (CHUNK / 16)       // 32 j-tiles per chunk

typedef __attribute__((ext_vector_type(8))) short bf16x8;
typedef __attribute__((ext_vector_type(4))) float f32x4;

// monotone float <-> uint encoding so atomicMax/atomicMin on uint order like floats
__device__ __forceinline__ unsigned fenc(float f) {
  unsigned u = __float_as_uint(f);
  return (u & 0x80000000u) ? ~u : (u | 0x80000000u);
}
__device__ __forceinline__ float fdec(unsigned u) {
  return (u & 0x80000000u) ? __uint_as_float(u & 0x7fffffffu) : __uint_as_float(~u);
}
__device__ __forceinline__ short f2bf(float f) {  // RNE fp32->bf16
  unsigned u = __float_as_uint(f);
  u += 0x7fffu + ((u >> 16) & 1u);
  return (short)(u >> 16);
}

// ---- kernel 1: build augmented bf16 arrays, sq, init accumulators, confusion, zero counters ----
// xa[row]  = [bf16(x), 1.0,         +32*onehot(cls), 0...]   (A operand)
// xbm[row] = [bf16(x), -(sq-128)/2, -32*onehot(cls), 0...]   (B operand)
// => g = dot(xa_i, xbm_j) = dot_ij - (sq_j-128)/2 - 1024*[same]
//    h = 128 - 2g = sq_j - 2dot + 2048*[same]
__global__ __launch_bounds__(256) void prep_k(const float* __restrict__ x,
                                              const int* __restrict__ tgt,
                                              const float* __restrict__ pred,
                                              short* __restrict__ xa,
                                              short* __restrict__ xbm,
                                              float* __restrict__ sq,
                                              unsigned* __restrict__ emax,
                                              unsigned* __restrict__ emin,
                                              int* __restrict__ conf,
                                              unsigned* __restrict__ ctrs) {
  if (blockIdx.x == 0 && threadIdx.x < NRG + 3) ctrs[threadIdx.x] = 0u;  // rg_done[32], g_done, Ssum, Csum

  const int wave = threadIdx.x >> 6;
  const int lane = threadIdx.x & 63;
  const int row  = blockIdx.x * 4 + wave;
  const float* p = x + (size_t)row * DIMX;
  const float a = p[lane];
  const float b = p[lane + 64];
  float s = a * a + b * b;
  #pragma unroll
  for (int m = 1; m < 64; m <<= 1) s += __shfl_xor(s, m, 64);

  short* pa = xa  + (size_t)row * DIM2;
  short* pb = xbm + (size_t)row * DIM2;
  pa[lane] = f2bf(a); pa[lane + 64] = f2bf(b);
  pb[lane] = f2bf(a); pb[lane + 64] = f2bf(b);

  const int cls = tgt[row];
  if (lane < 32) {
    short va, vb;
    if (lane == 0)          { va = (short)0x3F80; vb = f2bf(-0.5f * (s - C0)); }
    else if (lane <= NCLS)  { const bool hit = (lane - 1) == cls;
                              va = hit ? (short)0x4200 : (short)0;
                              vb = hit ? (short)0xC200 : (short)0; }
    else                    { va = 0; vb = 0; }
    pa[128 + lane] = va;
    pb[128 + lane] = vb;
  }

  if (lane == 0) {
    sq[row]   = s;
    emax[row] = fenc(-INFINITY);
    emin[row] = fenc(INFINITY);
    const float* pp = pred + (size_t)row * NCLS;
    float v[NCLS];
    #pragma unroll
    for (int c = 0; c < NCLS; ++c) v[c] = pp[c];
    float m1 = v[0]; int i1 = 0;
    #pragma unroll
    for (int c = 1; c < NCLS; ++c)
      if (v[c] > m1) { m1 = v[c]; i1 = c; }
    float m2 = -INFINITY, sum = 0.f;
    #pragma unroll
    for (int c = 0; c < NCLS; ++c) {
      sum += __expf(v[c] - m1);
      if (c != i1) m2 = fmaxf(m2, v[c]);
    }
    const float d01 = (1.f - __expf(m2 - m1)) / sum;
    conf[row] = (d01 <= GAPV) || (i1 != cls);
  }
}

// ---- kernel 2: Gram + hard mining + fused finalize ----
// Free-running waves: NO LDS, NO barriers in the hot loop. Each wave owns 64 rows
// (A register-resident), streams B-fragments directly from L2 with a 4-buffer
// modulo schedule at prefetch distance 2 (issue jt+2's loads while computing jt).
// 4 waves/block scan the same chunk -> L1 reuse. grid 32x16 = 512 blocks, 2/CU.
__global__ __launch_bounds__(256, 2) void gram_k(const short* __restrict__ xa,
                                                 const short* __restrict__ xbm,
                                                 const float* __restrict__ sq,
                                                 const int* __restrict__ conf,
                                                 unsigned* __restrict__ emax,
                                                 unsigned* __restrict__ emin,
                                                 unsigned* __restrict__ ctrs,
                                                 float* __restrict__ out) {
  __shared__ float red[2][4];
  __shared__ int   flag;
  const int tid  = threadIdx.x;
  const int wave = tid >> 6;
  const int lane = tid & 63;
  const int quad = lane >> 4;   // 0..3
  const int m16  = lane & 15;   // 0..15
  const int i0    = blockIdx.x * RGR + wave * 64;
  const int jbase = blockIdx.y * CHUNK;

  unsigned* rg_done = ctrs;                 // [NRG]
  unsigned* g_done  = ctrs + NRG;
  float*    Ssum    = (float*)(ctrs + NRG + 1);
  float*    Csum    = (float*)(ctrs + NRG + 2);

  // A fragments: rows i0 + r*16 + m16, k = ks*32 + quad*8 + e  (80 VGPRs)
  bf16x8 A[4][5];
  #pragma unroll
  for (int r = 0; r < 4; ++r) {
    const short* pa = xa + (size_t)(i0 + r * 16 + m16) * DIM2 + quad * 8;
    #pragma unroll
    for (int ks = 0; ks < 5; ++ks)
      A[r][ks] = *(const bf16x8*)(pa + ks * 32);
  }
  #pragma unroll
  for (int r = 0; r < 4; ++r)
    #pragma unroll
    for (int ks = 0; ks < 5; ++ks)
      asm("" : "+v"(A[r][ks]));   // pin: defeat rematerialization of A in the hot loop

  float gmin[4][4], gmax[4][4];
  #pragma unroll
  for (int r = 0; r < 4; ++r)
    #pragma unroll
    for (int q = 0; q < 4; ++q) { gmin[r][q] = INFINITY; gmax[r][q] = -INFINITY; }

  // B stream base for this lane: col j = jbase + jt*16 + m16, bytes [quad*16 + ks*64)
  const short* pb0 = xbm + (size_t)(jbase + m16) * DIM2 + quad * 8;

  // 4-buffer modulo pipeline, prefetch distance 2
  bf16x8 B[4][5];
  #pragma unroll
  for (int t = 0; t < 2; ++t) {
    const short* pl = pb0 + (size_t)t * 16 * DIM2;
    #pragma unroll
    for (int u = 0; u < 5; ++u) B[t][u] = *(const bf16x8*)(pl + u * 32);
  }

  for (int jt = 0; jt < NJ; jt += 4) {
    #pragma unroll
    for (int t = 0; t < 4; ++t) {
      // issue prefetch for (jt+t+2): lands in the buffer consumed 2 tiles ago
      const int j2 = (jt + t + 2) & (NJ - 1);   // wrap -> harmless re-read of tile 0/1
      const short* pl = pb0 + (size_t)j2 * 16 * DIM2;
      #pragma unroll
      for (int u = 0; u < 5; ++u)
        B[(t + 2) & 3][u] = *(const bf16x8*)(pl + u * 32);

      // compute on buffer t (data for tile jt+t)
      f32x4 acc[4];
      #pragma unroll
      for (int r = 0; r < 4; ++r) acc[r] = (f32x4){0.f, 0.f, 0.f, 0.f};
      #pragma unroll
      for (int ks = 0; ks < 5; ++ks)
        #pragma unroll
        for (int r = 0; r < 4; ++r)
          acc[r] = __builtin_amdgcn_mfma_f32_16x16x32_bf16(A[r][ks], B[t][ks], acc[r], 0, 0, 0);

      #pragma unroll
      for (int r = 0; r < 4; ++r)
        #pragma unroll
        for (int q = 0; q < 4; ++q) {
          gmin[r][q] = fminf(gmin[r][q], acc[r][q]);
          gmax[r][q] = fmaxf(gmax[r][q], acc[r][q]);
        }
    }
  }

  // reduce over the 16 cols held across m16 lanes (quad bits preserved)
  #pragma unroll
  for (int m = 1; m <= 8; m <<= 1)
    #pragma unroll
    for (int r = 0; r < 4; ++r)
      #pragma unroll
      for (int q = 0; q < 4; ++q) {
        gmin[r][q] = fminf(gmin[r][q], __shfl_xor(gmin[r][q], m, 64));
        gmax[r][q] = fmaxf(gmax[r][q], __shfl_xor(gmax[r][q], m, 64));
      }

  if (m16 == 0) {
    #pragma unroll
    for (int r = 0; r < 4; ++r)
      #pragma unroll
      for (int q = 0; q < 4; ++q) {
        const int row = i0 + r * 16 + quad * 4 + q;
        // hardest positive: max_same(sq_j - 2dot) = (128 - 2*gmin) - 2048
        atomicMax(&emax[row], fenc(C0 - 2.f * gmin[r][q] - BIAS));
        // hardest negative: min_diff(sq_j - 2dot) = 128 - 2*gmax
        atomicMin(&emin[row], fenc(C0 - 2.f * gmax[r][q]));
      }
  }

  // ---- fused finalize: last chunk-block of this rowgroup handles its 256 rows ----
  __syncthreads();   // block's atomics issued before counter bump
  if (tid == 0) {
    __threadfence();
    flag = (atomicAdd(&rg_done[blockIdx.x], 1u) == NCHUNK - 1u);
  }
  __syncthreads();
  if (!flag) return;
  __threadfence();   // acquire side

  const int row = blockIdx.x * RGR + tid;
  float ps = 0.f, pc = 0.f;
  if (conf[row]) {
    const float hi = fdec(atomicMax(&emax[row], 0u));           // identity read
    const float lo = fdec(atomicMin(&emin[row], 0xFFFFFFFFu));  // identity read
    const float ap = sqrtf(fmaxf(sq[row] + hi, 1e-12f));
    const float an = sqrtf(fmaxf(sq[row] + lo, 1e-12f));
    ps = fmaxf(ap - an, 0.f);
    pc = 1.f;
  }
  #pragma unroll
  for (int m = 1; m < 64; m <<= 1) {
    ps += __shfl_xor(ps, m, 64);
    pc += __shfl_xor(pc, m, 64);
  }
  if (lane == 0) { red[0][wave] = ps; red[1][wave] = pc; }
  __syncthreads();
  if (tid == 0) {
    float S = red[0][0] + red[0][1] + red[0][2] + red[0][3];
    float C = red[1][0] + red[1][1] + red[1][2] + red[1][3];
    atomicAdd(Ssum, S);
    atomicAdd(Csum, C);
    __threadfence();
    if (atomicAdd(g_done, 1u) == NRG - 1u) {
      const float St = atomicAdd(Ssum, 0.f);
      const float Ct = atomicAdd(Csum, 0.f);
      out[0] = (Ct > 0.f) ? (St / fmaxf(Ct, 1.f)) : 0.f;
    }
  }
}

extern "C" void kernel_launch(void* const* d_in, const int* in_sizes, int n_in,
                              void* d_out, int out_size, void* d_ws, size_t ws_size,
                              hipStream_t stream) {
  const float* x    = (const float*)d_in[0];
  const float* pred = (const float*)d_in[1];
  const int*   tgt  = (const int*)d_in[2];
  float* out = (float*)d_out;

  char* w = (char*)d_ws;
  const size_t arr_bytes = (size_t)NROWS * DIM2 * 2;  // 2.56 MiB each
  short*    xa   = (short*)w;
  short*    xbm  = (short*)(w + arr_bytes);
  float*    sq   = (float*)(w + 2 * arr_bytes);
  unsigned* emax = (unsigned*)(w + 2 * arr_bytes + (size_t)NROWS * 4);
  unsigned* emin = (unsigned*)(w + 2 * arr_bytes + (size_t)NROWS * 8);
  int*      conf = (int*)(w + 2 * arr_bytes + (size_t)NROWS * 12);
  unsigned* ctrs = (unsigned*)(w + 2 * arr_bytes + (size_t)NROWS * 16);  // rg_done[32], g_done, Ssum, Csum

  hipLaunchKernelGGL(prep_k, dim3(NROWS / 4), dim3(256), 0, stream,
                     x, tgt, pred, xa, xbm, sq, emax, emin, conf, ctrs);
  hipLaunchKernelGGL(gram_k, dim3(NRG, NCHUNK), dim3(256), 0, stream,
                     xa, xbm, sq, conf, emax, emin, ctrs, out);
}

// Round 8
// 91.577 us; speedup vs baseline: 1.1781x; 1.1693x over previous
//
#include <hip/hip_runtime.h>

#define NROWS 8192
#define DIMX  128            // raw feature dims
#define DIM2  160            // padded K: 128 data + 1 sq-dim + 10 one-hot + 21 zero
#define KSEG  20             // 16B segments per row (320 B)
#define PTS   20480          // shorts per 128-row panel tile (128*160)
#define NCLS  10
#define GAPV  0.4f
#define BIAS  2048.0f        // 2 * 32 * 32
#define C0    128.0f         // sq centering constant
#define RGR   256            // rows per block (4 waves x 64 rows)
#define NRG   (NROWS / RGR)        // 32 rowgroups
#define CHUNK 512            // cols per block
#define NCHUNK (NROWS / CHUNK)     // 16 col-chunks
#define SLAB  64             // cols per LDS slab
#define NSLAB (CHUNK / SLAB)       // 8 slabs

typedef __attribute__((ext_vector_type(8))) short bf16x8;
typedef __attribute__((ext_vector_type(4))) float f32x4;

// async 16B/lane global->LDS DMA (no VGPR roundtrip, compiler cannot collapse it)
#define GLOAD_LDS16(g, l)                                              \
  __builtin_amdgcn_global_load_lds(                                    \
      (const __attribute__((address_space(1))) void*)(g),              \
      (__attribute__((address_space(3))) void*)(l), 16, 0, 0)

// monotone float <-> uint encoding so atomicMax/atomicMin on uint order like floats
__device__ __forceinline__ unsigned fenc(float f) {
  unsigned u = __float_as_uint(f);
  return (u & 0x80000000u) ? ~u : (u | 0x80000000u);
}
__device__ __forceinline__ float fdec(unsigned u) {
  return (u & 0x80000000u) ? __uint_as_float(u & 0x7fffffffu) : __uint_as_float(~u);
}
__device__ __forceinline__ short f2bf(float f) {  // RNE fp32->bf16
  unsigned u = __float_as_uint(f);
  u += 0x7fffu + ((u >> 16) & 1u);
  return (short)(u >> 16);
}

// ---- kernel 1: build augmented bf16 PANEL arrays, sq, init accum, confusion, ctrs ----
// panel layout: short addr = (row>>7)*PTS + kseg*1024 + (row&127)*8 + within
// row content: [bf16(x[0..127]), (A:1.0 | B:-(s-128)/2), +/-32*onehot(cls), 0...]
__global__ __launch_bounds__(256) void prep_k(const float* __restrict__ x,
                                              const int* __restrict__ tgt,
                                              const float* __restrict__ pred,
                                              short* __restrict__ xa,
                                              short* __restrict__ xbm,
                                              float* __restrict__ sq,
                                              unsigned* __restrict__ emax,
                                              unsigned* __restrict__ emin,
                                              int* __restrict__ conf,
                                              unsigned* __restrict__ ctrs) {
  if (blockIdx.x == 0 && threadIdx.x < NRG + 3) ctrs[threadIdx.x] = 0u;

  const int wave = threadIdx.x >> 6;
  const int lane = threadIdx.x & 63;
  const int row  = blockIdx.x * 4 + wave;
  const float2 f2 = ((const float2*)(x + (size_t)row * DIMX))[lane];
  float s = f2.x * f2.x + f2.y * f2.y;
  #pragma unroll
  for (int m = 1; m < 64; m <<= 1) s += __shfl_xor(s, m, 64);

  const size_t base = (size_t)(row >> 7) * PTS + (size_t)(row & 127) * 8;
  // data shorts 2L,2L+1 -> kseg = L>>2, short-offset (L&3)*2
  {
    const unsigned lo = (unsigned short)f2bf(f2.x);
    const unsigned hi = (unsigned short)f2bf(f2.y);
    const unsigned u  = lo | (hi << 16);
    const size_t off = base + (size_t)(lane >> 2) * 1024 + (lane & 3) * 2;
    *(unsigned*)(xa + off)  = u;
    *(unsigned*)(xbm + off) = u;
  }
  const int cls = tgt[row];
  if (lane < 16) {  // aug shorts si = 128+2m, 129+2m  (m = lane)
    const int m = lane;
    const int si0 = 128 + 2 * m, si1 = si0 + 1;
    unsigned a0 = 0, a1 = 0, b0 = 0, b1 = 0;
    if (si0 == 128) { a0 = 0x3F80u; b0 = (unsigned short)f2bf(-0.5f * (s - C0)); }
    else if (si0 >= 129 && si0 <= 138 && cls == si0 - 129) { a0 = 0x4200u; b0 = 0xC200u; }
    if (si1 >= 129 && si1 <= 138 && cls == si1 - 129) { a1 = 0x4200u; b1 = 0xC200u; }
    const size_t off = base + (size_t)(16 + (m >> 2)) * 1024 + ((2 * m) & 6);
    *(unsigned*)(xa + off)  = a0 | (a1 << 16);
    *(unsigned*)(xbm + off) = b0 | (b1 << 16);
  }

  if (lane == 0) {
    sq[row]   = s;
    emax[row] = fenc(-INFINITY);
    emin[row] = fenc(INFINITY);
    const float* pp = pred + (size_t)row * NCLS;
    float v[NCLS];
    #pragma unroll
    for (int c = 0; c < NCLS; ++c) v[c] = pp[c];
    float m1 = v[0]; int i1 = 0;
    #pragma unroll
    for (int c = 1; c < NCLS; ++c)
      if (v[c] > m1) { m1 = v[c]; i1 = c; }
    float m2 = -INFINITY, sum = 0.f;
    #pragma unroll
    for (int c = 0; c < NCLS; ++c) {
      sum += __expf(v[c] - m1);
      if (c != i1) m2 = fmaxf(m2, v[c]);
    }
    const float d01 = (1.f - __expf(m2 - m1)) / sum;
    conf[row] = (d01 <= GAPV) || (i1 != cls);
  }
}

// ---- kernel 2: Gram + hard mining, m97-style DMA-staged B, fused finalize ----
// 4 waves/block, each owns 64 rows (A register-resident from panel: 256B-contiguous
// loads). B: 512-col chunk in 8 x 64-col slabs via global_load_lds (1KB-contiguous
// per instr), double-buffered; 2-barrier K-loop. LDS reads: 2-way banks = free.
__global__ __launch_bounds__(256, 2) void gram_k(const short* __restrict__ xa,
                                                 const short* __restrict__ xbm,
                                                 const float* __restrict__ sq,
                                                 const int* __restrict__ conf,
                                                 unsigned* __restrict__ emax,
                                                 unsigned* __restrict__ emin,
                                                 unsigned* __restrict__ ctrs,
                                                 float* __restrict__ out) {
  __shared__ short lds[2][KSEG * 512];   // per buf: 20 ksegs x 64 cols x 8 shorts = 20 KB
  __shared__ float red[2][4];
  __shared__ int   flag;
  const int tid  = threadIdx.x;
  const int wave = tid >> 6;
  const int lane = tid & 63;
  const int quad = lane >> 4;   // 0..3
  const int m16  = lane & 15;   // 0..15
  const int bx = blockIdx.x, by = blockIdx.y;
  const int i0 = bx * RGR + wave * 64;

  unsigned* rg_done = ctrs;                 // [NRG]
  unsigned* g_done  = ctrs + NRG;
  float*    Ssum    = (float*)(ctrs + NRG + 1);
  float*    Csum    = (float*)(ctrs + NRG + 2);

  // A fragments from panel: rows i0 + rt*16 + m16, kseg = ks*4 + quad
  bf16x8 A[4][5];
  #pragma unroll
  for (int rt = 0; rt < 4; ++rt) {
    const int rbase = wave * 64 + rt * 16;               // 0..240 within 256-row block
    const short* pa = xa + (size_t)(bx * 2 + (rbase >> 7)) * PTS
                         + (size_t)((rbase & 127) + m16) * 8;
    #pragma unroll
    for (int ks = 0; ks < 5; ++ks)
      A[rt][ks] = *(const bf16x8*)(pa + (size_t)(ks * 4 + quad) * 1024);
  }
  #pragma unroll
  for (int rt = 0; rt < 4; ++rt)
    #pragma unroll
    for (int ks = 0; ks < 5; ++ks)
      asm("" : "+v"(A[rt][ks]));   // keep A resident

  float gmin[4][4], gmax[4][4];
  #pragma unroll
  for (int r = 0; r < 4; ++r)
    #pragma unroll
    for (int q = 0; q < 4; ++q) { gmin[r][q] = INFINITY; gmax[r][q] = -INFINITY; }

  // DMA: slab s covers cols by*512 + s*64; each wave stages ksegs wave*5..wave*5+4.
  // src: 1KB contiguous (panel kseg region, half-tile);  dst: lds[buf][kseg][lane*16B]
  #pragma unroll
  for (int u = 0; u < 5; ++u) {
    const int kseg = wave * 5 + u;
    const short* src = xbm + (size_t)(by * 4) * PTS + (size_t)kseg * 1024 + lane * 8;
    GLOAD_LDS16(src, &lds[0][kseg * 512 + lane * 8]);
  }

  for (int s = 0; s < NSLAB; ++s) {
    __syncthreads();   // drains this wave's DMA (vmcnt0) + syncs buf ready
    if (s + 1 < NSLAB) {   // issue DMA for slab s+1 into the other buffer
      const int ptc  = by * 4 + ((s + 1) >> 1);
      const int half = (s + 1) & 1;
      #pragma unroll
      for (int u = 0; u < 5; ++u) {
        const int kseg = wave * 5 + u;
        const short* src = xbm + (size_t)ptc * PTS + (size_t)kseg * 1024 + half * 512 + lane * 8;
        GLOAD_LDS16(src, &lds[(s + 1) & 1][kseg * 512 + lane * 8]);
      }
    }
    // compute slab s from lds[s&1]: 4 j-tiles of 16 cols
    const short* buf = lds[s & 1];
    #pragma unroll
    for (int jt = 0; jt < 4; ++jt) {
      bf16x8 B[5];
      #pragma unroll
      for (int ks = 0; ks < 5; ++ks)
        B[ks] = *(const bf16x8*)(buf + (ks * 4 + quad) * 512 + (jt * 16 + m16) * 8);

      f32x4 acc[4];
      #pragma unroll
      for (int r = 0; r < 4; ++r) acc[r] = (f32x4){0.f, 0.f, 0.f, 0.f};
      #pragma unroll
      for (int ks = 0; ks < 5; ++ks)
        #pragma unroll
        for (int r = 0; r < 4; ++r)
          acc[r] = __builtin_amdgcn_mfma_f32_16x16x32_bf16(A[r][ks], B[ks], acc[r], 0, 0, 0);

      #pragma unroll
      for (int r = 0; r < 4; ++r)
        #pragma unroll
        for (int q = 0; q < 4; ++q) {
          gmin[r][q] = fminf(gmin[r][q], acc[r][q]);
          gmax[r][q] = fmaxf(gmax[r][q], acc[r][q]);
        }
    }
  }

  // reduce over the 16 cols held across m16 lanes (quad bits preserved)
  #pragma unroll
  for (int m = 1; m <= 8; m <<= 1)
    #pragma unroll
    for (int r = 0; r < 4; ++r)
      #pragma unroll
      for (int q = 0; q < 4; ++q) {
        gmin[r][q] = fminf(gmin[r][q], __shfl_xor(gmin[r][q], m, 64));
        gmax[r][q] = fmaxf(gmax[r][q], __shfl_xor(gmax[r][q], m, 64));
      }

  if (m16 == 0) {
    #pragma unroll
    for (int r = 0; r < 4; ++r)
      #pragma unroll
      for (int q = 0; q < 4; ++q) {
        const int row = i0 + r * 16 + quad * 4 + q;
        // hardest positive: max_same(sq_j - 2dot) = (128 - 2*gmin) - 2048
        atomicMax(&emax[row], fenc(C0 - 2.f * gmin[r][q] - BIAS));
        // hardest negative: min_diff(sq_j - 2dot) = 128 - 2*gmax
        atomicMin(&emin[row], fenc(C0 - 2.f * gmax[r][q]));
      }
  }

  // ---- fused finalize: last chunk-block of this rowgroup handles its 256 rows ----
  __syncthreads();
  if (tid == 0) {
    __threadfence();
    flag = (atomicAdd(&rg_done[blockIdx.x], 1u) == NCHUNK - 1u);
  }
  __syncthreads();
  if (!flag) return;
  __threadfence();

  const int row = bx * RGR + tid;
  float ps = 0.f, pc = 0.f;
  if (conf[row]) {
    const float hi = fdec(atomicMax(&emax[row], 0u));           // identity read
    const float lo = fdec(atomicMin(&emin[row], 0xFFFFFFFFu));  // identity read
    const float ap = sqrtf(fmaxf(sq[row] + hi, 1e-12f));
    const float an = sqrtf(fmaxf(sq[row] + lo, 1e-12f));
    ps = fmaxf(ap - an, 0.f);
    pc = 1.f;
  }
  #pragma unroll
  for (int m = 1; m < 64; m <<= 1) {
    ps += __shfl_xor(ps, m, 64);
    pc += __shfl_xor(pc, m, 64);
  }
  if (lane == 0) { red[0][wave] = ps; red[1][wave] = pc; }
  __syncthreads();
  if (tid == 0) {
    float S = red[0][0] + red[0][1] + red[0][2] + red[0][3];
    float C = red[1][0] + red[1][1] + red[1][2] + red[1][3];
    atomicAdd(Ssum, S);
    atomicAdd(Csum, C);
    __threadfence();
    if (atomicAdd(g_done, 1u) == NRG - 1u) {
      const float St = atomicAdd(Ssum, 0.f);
      const float Ct = atomicAdd(Csum, 0.f);
      out[0] = (Ct > 0.f) ? (St / fmaxf(Ct, 1.f)) : 0.f;
    }
  }
}

extern "C" void kernel_launch(void* const* d_in, const int* in_sizes, int n_in,
                              void* d_out, int out_size, void* d_ws, size_t ws_size,
                              hipStream_t stream) {
  const float* x    = (const float*)d_in[0];
  const float* pred = (const float*)d_in[1];
  const int*   tgt  = (const int*)d_in[2];
  float* out = (float*)d_out;

  char* w = (char*)d_ws;
  const size_t arr_bytes = (size_t)NROWS * DIM2 * 2;  // 2.62 MiB each (panel layout)
  short*    xa   = (short*)w;
  short*    xbm  = (short*)(w + arr_bytes);
  float*    sq   = (float*)(w + 2 * arr_bytes);
  unsigned* emax = (unsigned*)(w + 2 * arr_bytes + (size_t)NROWS * 4);
  unsigned* emin = (unsigned*)(w + 2 * arr_bytes + (size_t)NROWS * 8);
  int*      conf = (int*)(w + 2 * arr_bytes + (size_t)NROWS * 12);
  unsigned* ctrs = (unsigned*)(w + 2 * arr_bytes + (size_t)NROWS * 16);

  hipLaunchKernelGGL(prep_k, dim3(NROWS / 4), dim3(256), 0, stream,
                     x, tgt, pred, xa, xbm, sq, emax, emin, conf, ctrs);
  hipLaunchKernelGGL(gram_k, dim3(NRG, NCHUNK), dim3(256), 0, stream,
                     xa, xbm, sq, conf, emax, emin, ctrs, out);
}